// Round 1
// baseline (247.718 us; speedup 1.0000x reference)
//
#include <hip/hip_runtime.h>
#include <hip/hip_bf16.h>

// ---------------------------------------------------------------------------
// LocalAttention: out = (softmax_mask(QK^T*s) V) Wo + bo, sliding causal W=256
// S=4096, D=1024, H=16, hd=64. All compute in bf16 MFMA (16x16x32), f32 accum.
// ---------------------------------------------------------------------------

typedef __attribute__((ext_vector_type(8))) short bf16x8;
typedef __attribute__((ext_vector_type(4))) float f32x4;

#define S_LEN 4096
#define D_MODEL 1024
#define N_HEADS 16
#define HEAD_DIM 64
#define WINDOW 256

static __device__ __forceinline__ unsigned short f2bfbits(float f) {
    __hip_bfloat16 h = __float2bfloat16(f);
    unsigned short u;
    __builtin_memcpy(&u, &h, sizeof(u));
    return u;
}

// ---------------- cast f32 -> bf16 (contiguous) ----------------
__global__ __launch_bounds__(256) void cast_bf16_k(const float* __restrict__ src,
                                                   unsigned short* __restrict__ dst,
                                                   int n) {
    int i = (blockIdx.x * 256 + threadIdx.x) * 4;
    if (i < n) {
        float4 v = *(const float4*)(src + i);
        ushort4 o;
        o.x = f2bfbits(v.x); o.y = f2bfbits(v.y);
        o.z = f2bfbits(v.z); o.w = f2bfbits(v.w);
        *(ushort4*)(dst + i) = o;
    }
}

// ---------------- cast + transpose: src[K][N] f32 -> dst[N][K] bf16 ----------
__global__ __launch_bounds__(256) void cast_transpose_k(const float* __restrict__ src,
                                                        __hip_bfloat16* __restrict__ dst,
                                                        int Kd, int Nd) {
    __shared__ __hip_bfloat16 tile[64][65];
    const int n0 = blockIdx.x * 64, k0 = blockIdx.y * 64;
    const int t = threadIdx.x;
    for (int c = t; c < 1024; c += 256) {
        int r = c >> 4, c4 = (c & 15) * 4;
        float4 v = *(const float4*)(src + (size_t)(k0 + r) * Nd + n0 + c4);
        tile[r][c4 + 0] = __float2bfloat16(v.x);
        tile[r][c4 + 1] = __float2bfloat16(v.y);
        tile[r][c4 + 2] = __float2bfloat16(v.z);
        tile[r][c4 + 3] = __float2bfloat16(v.w);
    }
    __syncthreads();
    for (int c = t; c < 1024; c += 256) {
        int rr = c >> 4, c4 = (c & 15) * 4;
        ushort4 o;
        unsigned short u0, u1, u2, u3;
        __builtin_memcpy(&u0, &tile[c4 + 0][rr], 2);
        __builtin_memcpy(&u1, &tile[c4 + 1][rr], 2);
        __builtin_memcpy(&u2, &tile[c4 + 2][rr], 2);
        __builtin_memcpy(&u3, &tile[c4 + 3][rr], 2);
        o.x = u0; o.y = u1; o.z = u2; o.w = u3;
        *(ushort4*)((unsigned short*)dst + (size_t)(n0 + rr) * Kd + k0 + c4) = o;
    }
}

// ---------------- GEMM: C[M][N] = A[M][K](bf16) * Bt[N][K](bf16)^T + bias ----
// Bt is B pre-transposed so both stagings are coalesced uint4 loads.
// 128x128 tile, BK=32, 4 waves, each wave 64x64 (4x4 frags of 16x16x32).
template <bool OUT_BF16>
__global__ __launch_bounds__(256) void gemm_bias_k(const __hip_bfloat16* __restrict__ A,
                                                   const __hip_bfloat16* __restrict__ Bt,
                                                   const float* __restrict__ bias,
                                                   void* __restrict__ Cout,
                                                   int M, int N, int K) {
    constexpr int LDA = 40;  // 32 + 8 pad, keeps 16B alignment (80B row pitch)
    __shared__ __align__(16) __hip_bfloat16 As[128 * LDA];
    __shared__ __align__(16) __hip_bfloat16 Bs[128 * LDA];

    const int m0 = blockIdx.y * 128, n0 = blockIdx.x * 128;
    const int t = threadIdx.x;
    const int wave = t >> 6, lane = t & 63;
    const int quad = lane >> 4, l16 = lane & 15;
    const int wm = (wave & 1) * 64, wn = (wave >> 1) * 64;

    f32x4 acc[4][4];
#pragma unroll
    for (int mi = 0; mi < 4; ++mi)
#pragma unroll
        for (int ni = 0; ni < 4; ++ni) acc[mi][ni] = (f32x4){0.f, 0.f, 0.f, 0.f};

    for (int k0 = 0; k0 < K; k0 += 32) {
#pragma unroll
        for (int c = t; c < 512; c += 256) {
            int row = c >> 2, col8 = (c & 3) * 8;
            *(uint4*)&As[row * LDA + col8] =
                *(const uint4*)(A + (size_t)(m0 + row) * K + k0 + col8);
            *(uint4*)&Bs[row * LDA + col8] =
                *(const uint4*)(Bt + (size_t)(n0 + row) * K + k0 + col8);
        }
        __syncthreads();

        bf16x8 af[4], bfr[4];
#pragma unroll
        for (int mi = 0; mi < 4; ++mi)
            af[mi] = *(const bf16x8*)&As[(wm + mi * 16 + l16) * LDA + quad * 8];
#pragma unroll
        for (int ni = 0; ni < 4; ++ni)
            bfr[ni] = *(const bf16x8*)&Bs[(wn + ni * 16 + l16) * LDA + quad * 8];
#pragma unroll
        for (int mi = 0; mi < 4; ++mi)
#pragma unroll
            for (int ni = 0; ni < 4; ++ni)
                acc[mi][ni] = __builtin_amdgcn_mfma_f32_16x16x32_bf16(
                    af[mi], bfr[ni], acc[mi][ni], 0, 0, 0);
        __syncthreads();
    }

    // epilogue: C row = quad*4+r, col = l16 (per-16x16 frag)
#pragma unroll
    for (int mi = 0; mi < 4; ++mi) {
#pragma unroll
        for (int ni = 0; ni < 4; ++ni) {
#pragma unroll
            for (int r = 0; r < 4; ++r) {
                int row = m0 + wm + mi * 16 + quad * 4 + r;
                int col = n0 + wn + ni * 16 + l16;
                float v = acc[mi][ni][r] + bias[col];
                if (OUT_BF16)
                    ((__hip_bfloat16*)Cout)[(size_t)row * N + col] = __float2bfloat16(v);
                else
                    ((float*)Cout)[(size_t)row * N + col] = v;
            }
        }
    }
}

// ---------------- sliding-window flash attention ----------------
// block: 1 head x 64 queries (4 waves x 16 q rows). 5 key tiles of 64 cover
// [i0-256, i0+64). Online softmax in exp2 domain (scale*log2e folded).
__global__ __launch_bounds__(256) void attn_k(const __hip_bfloat16* __restrict__ Q,
                                              const __hip_bfloat16* __restrict__ K,
                                              const __hip_bfloat16* __restrict__ V,
                                              __hip_bfloat16* __restrict__ AO) {
    __shared__ __align__(16) __hip_bfloat16 Qs[64 * 72];
    __shared__ __align__(16) __hip_bfloat16 Ks[64 * 72];
    __shared__ __align__(16) __hip_bfloat16 Vt[64 * 72];  // transposed: [hd][key]
    __shared__ __align__(16) __hip_bfloat16 Ps[4 * 16 * 72];

    const int h = blockIdx.y;
    const int i0 = blockIdx.x * 64;
    const int t = threadIdx.x;
    const int wave = t >> 6, lane = t & 63;
    const int quad = lane >> 4, l16 = lane & 15;
    const float sc = 0.125f * 1.44269504088896f;  // 1/sqrt(64) * log2(e)

    // stage Q tile [64 rows][64 hd]
    for (int c = t; c < 512; c += 256) {
        int row = c >> 3, c8 = (c & 7) * 8;
        *(uint4*)&Qs[row * 72 + c8] =
            *(const uint4*)(Q + (size_t)(i0 + row) * D_MODEL + h * HEAD_DIM + c8);
    }
    __syncthreads();

    bf16x8 aq[2];
#pragma unroll
    for (int kk = 0; kk < 2; ++kk)
        aq[kk] = *(const bf16x8*)&Qs[(wave * 16 + l16) * 72 + kk * 32 + quad * 8];

    float mrow[4], lrow[4];
    f32x4 Ov[4];
#pragma unroll
    for (int r = 0; r < 4; ++r) { mrow[r] = -3.0e38f; lrow[r] = 0.f; }
#pragma unroll
    for (int no = 0; no < 4; ++no) Ov[no] = (f32x4){0.f, 0.f, 0.f, 0.f};

    for (int tt = 0; tt < 5; ++tt) {
        const int tb = i0 - WINDOW + tt * 64;
        if (tb < 0) continue;  // uniform across block

        // stage K tile (natural) and V tile (transposed)
        for (int c = t; c < 512; c += 256) {
            int row = c >> 3, c8 = (c & 7) * 8;
            *(uint4*)&Ks[row * 72 + c8] =
                *(const uint4*)(K + (size_t)(tb + row) * D_MODEL + h * HEAD_DIM + c8);
            uint4 v = *(const uint4*)(V + (size_t)(tb + row) * D_MODEL + h * HEAD_DIM + c8);
            const __hip_bfloat16* pv = (const __hip_bfloat16*)&v;
#pragma unroll
            for (int j = 0; j < 8; ++j) Vt[(c8 + j) * 72 + row] = pv[j];
        }
        __syncthreads();

        // S = Q K^T  (M=16 q rows, N=64 keys, K=64 hd)
        f32x4 s[4];
#pragma unroll
        for (int ni = 0; ni < 4; ++ni) s[ni] = (f32x4){0.f, 0.f, 0.f, 0.f};
#pragma unroll
        for (int kk = 0; kk < 2; ++kk)
#pragma unroll
            for (int ni = 0; ni < 4; ++ni) {
                bf16x8 bk = *(const bf16x8*)&Ks[(ni * 16 + l16) * 72 + kk * 32 + quad * 8];
                s[ni] = __builtin_amdgcn_mfma_f32_16x16x32_bf16(aq[kk], bk, s[ni], 0, 0, 0);
            }

        // mask + online softmax (exp2 domain)
        const int irow0 = i0 + wave * 16 + quad * 4;
        float tv[4][4], rmax[4];
#pragma unroll
        for (int r = 0; r < 4; ++r) rmax[r] = -3.0e38f;
#pragma unroll
        for (int ni = 0; ni < 4; ++ni) {
            int j = tb + ni * 16 + l16;
#pragma unroll
            for (int r = 0; r < 4; ++r) {
                int i = irow0 + r;
                float v = s[ni][r] * sc;
                bool ok = (j <= i) && (i - j < WINDOW);
                v = ok ? v : -3.0e38f;
                tv[ni][r] = v;
                rmax[r] = fmaxf(rmax[r], v);
            }
        }
#pragma unroll
        for (int r = 0; r < 4; ++r) {
            rmax[r] = fmaxf(rmax[r], __shfl_xor(rmax[r], 1));
            rmax[r] = fmaxf(rmax[r], __shfl_xor(rmax[r], 2));
            rmax[r] = fmaxf(rmax[r], __shfl_xor(rmax[r], 4));
            rmax[r] = fmaxf(rmax[r], __shfl_xor(rmax[r], 8));
        }
        float alpha[4], rsum[4];
#pragma unroll
        for (int r = 0; r < 4; ++r) {
            float mn = fmaxf(mrow[r], rmax[r]);
            alpha[r] = exp2f(mrow[r] - mn);
            mrow[r] = mn;
            rsum[r] = 0.f;
        }
        float p[4][4];
#pragma unroll
        for (int ni = 0; ni < 4; ++ni)
#pragma unroll
            for (int r = 0; r < 4; ++r) {
                p[ni][r] = exp2f(tv[ni][r] - mrow[r]);
                rsum[r] += p[ni][r];
            }
#pragma unroll
        for (int r = 0; r < 4; ++r) {
            rsum[r] += __shfl_xor(rsum[r], 1);
            rsum[r] += __shfl_xor(rsum[r], 2);
            rsum[r] += __shfl_xor(rsum[r], 4);
            rsum[r] += __shfl_xor(rsum[r], 8);
            lrow[r] = lrow[r] * alpha[r] + rsum[r];
        }
#pragma unroll
        for (int no = 0; no < 4; ++no)
#pragma unroll
            for (int r = 0; r < 4; ++r) Ov[no][r] *= alpha[r];

        // P: C-layout -> LDS -> A-layout (per-wave region, no barrier needed)
#pragma unroll
        for (int ni = 0; ni < 4; ++ni)
#pragma unroll
            for (int r = 0; r < 4; ++r)
                Ps[(wave * 16 + quad * 4 + r) * 72 + ni * 16 + l16] =
                    __float2bfloat16(p[ni][r]);

        // O += P V  (M=16, N=64 hd, K=64 keys)
#pragma unroll
        for (int kk = 0; kk < 2; ++kk) {
            bf16x8 ap = *(const bf16x8*)&Ps[(wave * 16 + l16) * 72 + kk * 32 + quad * 8];
#pragma unroll
            for (int no = 0; no < 4; ++no) {
                bf16x8 bv = *(const bf16x8*)&Vt[(no * 16 + l16) * 72 + kk * 32 + quad * 8];
                Ov[no] = __builtin_amdgcn_mfma_f32_16x16x32_bf16(ap, bv, Ov[no], 0, 0, 0);
            }
        }
        __syncthreads();  // protect Ks/Vt before next tile's staging
    }

    // normalize + store
    float inv[4];
#pragma unroll
    for (int r = 0; r < 4; ++r) inv[r] = 1.0f / lrow[r];
#pragma unroll
    for (int no = 0; no < 4; ++no)
#pragma unroll
        for (int r = 0; r < 4; ++r) {
            int i = i0 + wave * 16 + quad * 4 + r;
            AO[(size_t)i * D_MODEL + h * HEAD_DIM + no * 16 + l16] =
                __float2bfloat16(Ov[no][r] * inv[r]);
        }
}

// ---------------------------------------------------------------------------
extern "C" void kernel_launch(void* const* d_in, const int* in_sizes, int n_in,
                              void* d_out, int out_size, void* d_ws, size_t ws_size,
                              hipStream_t stream) {
    const float* x  = (const float*)d_in[0];
    const float* Wq = (const float*)d_in[1];
    const float* Wk = (const float*)d_in[2];
    const float* Wv = (const float*)d_in[3];
    const float* Wo = (const float*)d_in[4];
    const float* bq = (const float*)d_in[5];
    const float* bk = (const float*)d_in[6];
    const float* bv = (const float*)d_in[7];
    const float* bo = (const float*)d_in[8];
    float* out = (float*)d_out;

    char* w = (char*)d_ws;
    const size_t MB = 1u << 20;
    __hip_bfloat16* xb  = (__hip_bfloat16*)(w + 0 * MB);   // 4096x1024 (8 MB)
    __hip_bfloat16* Wqt = (__hip_bfloat16*)(w + 8 * MB);   // [N][K] (2 MB each)
    __hip_bfloat16* Wkt = (__hip_bfloat16*)(w + 10 * MB);
    __hip_bfloat16* Wvt = (__hip_bfloat16*)(w + 12 * MB);
    __hip_bfloat16* Wot = (__hip_bfloat16*)(w + 14 * MB);
    __hip_bfloat16* Qp  = (__hip_bfloat16*)(w + 16 * MB);  // 8 MB
    __hip_bfloat16* Kp  = (__hip_bfloat16*)(w + 24 * MB);
    __hip_bfloat16* Vp  = (__hip_bfloat16*)(w + 32 * MB);
    __hip_bfloat16* AO  = (__hip_bfloat16*)(w + 40 * MB);  // 8 MB, end = 48 MB

    // casts
    cast_bf16_k<<<4096, 256, 0, stream>>>(x, (unsigned short*)xb, S_LEN * D_MODEL);
    dim3 tg(16, 16);
    cast_transpose_k<<<tg, 256, 0, stream>>>(Wq, Wqt, D_MODEL, D_MODEL);
    cast_transpose_k<<<tg, 256, 0, stream>>>(Wk, Wkt, D_MODEL, D_MODEL);
    cast_transpose_k<<<tg, 256, 0, stream>>>(Wv, Wvt, D_MODEL, D_MODEL);
    cast_transpose_k<<<tg, 256, 0, stream>>>(Wo, Wot, D_MODEL, D_MODEL);

    // projections
    dim3 gg(D_MODEL / 128, S_LEN / 128);
    gemm_bias_k<true><<<gg, 256, 0, stream>>>(xb, Wqt, bq, Qp, S_LEN, D_MODEL, D_MODEL);
    gemm_bias_k<true><<<gg, 256, 0, stream>>>(xb, Wkt, bk, Kp, S_LEN, D_MODEL, D_MODEL);
    gemm_bias_k<true><<<gg, 256, 0, stream>>>(xb, Wvt, bv, Vp, S_LEN, D_MODEL, D_MODEL);

    // attention
    dim3 ag(S_LEN / 64, N_HEADS);
    attn_k<<<ag, 256, 0, stream>>>(Qp, Kp, Vp, AO);

    // output projection -> f32
    gemm_bias_k<false><<<gg, 256, 0, stream>>>(AO, Wot, bo, out, S_LEN, D_MODEL, D_MODEL);
}

// Round 2
// 187.428 us; speedup vs baseline: 1.3217x; 1.3217x over previous
//
#include <hip/hip_runtime.h>
#include <hip/hip_bf16.h>

// ---------------------------------------------------------------------------
// LocalAttention: out = (softmax_mask(QK^T*s) V) Wo + bo, sliding causal W=256
// S=4096, D=1024, H=16, hd=64. bf16 MFMA (16x16x32), f32 accum.
// R2: global_load_lds GEMM staging, fused QKV GEMM (N=3072), fused prep,
//     b32-packed V transpose in attention. 4 launches total.
// ---------------------------------------------------------------------------

typedef __attribute__((ext_vector_type(8))) short bf16x8;
typedef __attribute__((ext_vector_type(4))) float f32x4;

#define S_LEN 4096
#define D_MODEL 1024
#define N_HEADS 16
#define HEAD_DIM 64
#define WINDOW 256
#define QKV_LD 3072

static __device__ __forceinline__ unsigned short f2bfbits(float f) {
    __hip_bfloat16 h = __float2bfloat16(f);
    unsigned short u;
    __builtin_memcpy(&u, &h, sizeof(u));
    return u;
}

typedef const __attribute__((address_space(1))) void c_gvoid;
typedef __attribute__((address_space(3))) void lvoid;
static __device__ __forceinline__ void gload16(const void* g, void* l) {
    __builtin_amdgcn_global_load_lds((c_gvoid*)g, (lvoid*)l, 16, 0, 0);
}

// ---------------- fused prep: x-cast, W transposes, bias concat -------------
// blocks [0,2048): cast x (2048 elems each)
// blocks [2048,3072): W transposes, 256 blocks per matrix (Wq,Wk,Wv,Wo)
// block 3072: bias concat
__global__ __launch_bounds__(256) void prep_k(const float* __restrict__ x,
                                              const float* __restrict__ Wq,
                                              const float* __restrict__ Wk,
                                              const float* __restrict__ Wv,
                                              const float* __restrict__ Wo,
                                              const float* __restrict__ bq,
                                              const float* __restrict__ bk,
                                              const float* __restrict__ bv,
                                              unsigned short* __restrict__ xb,
                                              __hip_bfloat16* __restrict__ Wqkvt,
                                              __hip_bfloat16* __restrict__ Wot,
                                              float* __restrict__ bias_cat) {
    const int b = blockIdx.x;
    const int t = threadIdx.x;
    if (b < 2048) {
        // cast x -> bf16
        int i = b * 2048 + t * 8;
        float4 v0 = *(const float4*)(x + i);
        float4 v1 = *(const float4*)(x + i + 4);
        ushort4 o0, o1;
        o0.x = f2bfbits(v0.x); o0.y = f2bfbits(v0.y);
        o0.z = f2bfbits(v0.z); o0.w = f2bfbits(v0.w);
        o1.x = f2bfbits(v1.x); o1.y = f2bfbits(v1.y);
        o1.z = f2bfbits(v1.z); o1.w = f2bfbits(v1.w);
        *(ushort4*)(xb + i) = o0;
        *(ushort4*)(xb + i + 4) = o1;
        return;
    }
    if (b < 3072) {
        // cast + transpose one 64x64 tile: src[K][N] f32 -> dst[N][K] bf16
        __shared__ __hip_bfloat16 tile[64][65];
        const int m = (b - 2048) >> 8;          // which matrix
        const int tid = (b - 2048) & 255;
        const int n0 = (tid & 15) * 64, k0 = (tid >> 4) * 64;
        const float* src = (m == 0) ? Wq : (m == 1) ? Wk : (m == 2) ? Wv : Wo;
        __hip_bfloat16* dst = (m < 3) ? (Wqkvt + (size_t)m * D_MODEL * D_MODEL) : Wot;
        for (int c = t; c < 1024; c += 256) {
            int r = c >> 4, c4 = (c & 15) * 4;
            float4 v = *(const float4*)(src + (size_t)(k0 + r) * D_MODEL + n0 + c4);
            tile[r][c4 + 0] = __float2bfloat16(v.x);
            tile[r][c4 + 1] = __float2bfloat16(v.y);
            tile[r][c4 + 2] = __float2bfloat16(v.z);
            tile[r][c4 + 3] = __float2bfloat16(v.w);
        }
        __syncthreads();
        for (int c = t; c < 1024; c += 256) {
            int rr = c >> 4, c4 = (c & 15) * 4;
            ushort4 o;
            unsigned short u0, u1, u2, u3;
            __builtin_memcpy(&u0, &tile[c4 + 0][rr], 2);
            __builtin_memcpy(&u1, &tile[c4 + 1][rr], 2);
            __builtin_memcpy(&u2, &tile[c4 + 2][rr], 2);
            __builtin_memcpy(&u3, &tile[c4 + 3][rr], 2);
            o.x = u0; o.y = u1; o.z = u2; o.w = u3;
            *(ushort4*)((unsigned short*)dst + (size_t)(n0 + rr) * D_MODEL + k0 + c4) = o;
        }
        return;
    }
    // bias concat: [bq | bk | bv]
    for (int c = t; c < 3 * D_MODEL; c += 256) {
        float v = (c < 1024) ? bq[c] : (c < 2048) ? bk[c - 1024] : bv[c - 2048];
        bias_cat[c] = v;
    }
}

// ---------------- GEMM: C[M][N] = A[M][K](bf16) * Bt[N][K](bf16)^T + bias ----
// 128x128 tile, BK=32, 4 waves (64x64 each, 4x4 frags of 16x16x32).
// Staging via global_load_lds width=16 into UNPADDED LDS (m97 recipe).
template <bool OUT_BF16>
__global__ __launch_bounds__(256) void gemm_bias_k(const __hip_bfloat16* __restrict__ A,
                                                   const __hip_bfloat16* __restrict__ Bt,
                                                   const float* __restrict__ bias,
                                                   void* __restrict__ Cout,
                                                   int M, int N, int K) {
    __shared__ __align__(16) __hip_bfloat16 As[128 * 32];
    __shared__ __align__(16) __hip_bfloat16 Bs[128 * 32];

    const int m0 = blockIdx.y * 128, n0 = blockIdx.x * 128;
    const int t = threadIdx.x;
    const int wave = t >> 6, lane = t & 63;
    const int quad = lane >> 4, l16 = lane & 15;
    const int wm = (wave & 1) * 64, wn = (wave >> 1) * 64;

    // staging coords: wave handles 16 rows/pass (lane/4 = row, lane%4 = 16B chunk)
    const int srow = wave * 16 + (lane >> 2);    // 0..63
    const int scol = (lane & 3) * 8;             // bf16 elems: 0,8,16,24

    f32x4 acc[4][4];
#pragma unroll
    for (int mi = 0; mi < 4; ++mi)
#pragma unroll
        for (int ni = 0; ni < 4; ++ni) acc[mi][ni] = (f32x4){0.f, 0.f, 0.f, 0.f};

    const __hip_bfloat16* gA = A + (size_t)(m0 + srow) * K + scol;
    const __hip_bfloat16* gB = Bt + (size_t)(n0 + srow) * K + scol;
    const size_t strideA = (size_t)64 * K;

    for (int k0 = 0; k0 < K; k0 += 32) {
        gload16(gA + k0, &As[srow * 32 + scol]);
        gload16(gA + k0 + strideA, &As[(srow + 64) * 32 + scol]);
        gload16(gB + k0, &Bs[srow * 32 + scol]);
        gload16(gB + k0 + strideA, &Bs[(srow + 64) * 32 + scol]);
        __syncthreads();

        bf16x8 af[4], bfr[4];
#pragma unroll
        for (int mi = 0; mi < 4; ++mi)
            af[mi] = *(const bf16x8*)&As[(wm + mi * 16 + l16) * 32 + quad * 8];
#pragma unroll
        for (int ni = 0; ni < 4; ++ni)
            bfr[ni] = *(const bf16x8*)&Bs[(wn + ni * 16 + l16) * 32 + quad * 8];
#pragma unroll
        for (int mi = 0; mi < 4; ++mi)
#pragma unroll
            for (int ni = 0; ni < 4; ++ni)
                acc[mi][ni] = __builtin_amdgcn_mfma_f32_16x16x32_bf16(
                    af[mi], bfr[ni], acc[mi][ni], 0, 0, 0);
        __syncthreads();
    }

    // epilogue: C row = quad*4+r, col = l16 (per 16x16 frag)
#pragma unroll
    for (int mi = 0; mi < 4; ++mi) {
#pragma unroll
        for (int ni = 0; ni < 4; ++ni) {
#pragma unroll
            for (int r = 0; r < 4; ++r) {
                int row = m0 + wm + mi * 16 + quad * 4 + r;
                int col = n0 + wn + ni * 16 + l16;
                float v = acc[mi][ni][r] + bias[col];
                if (OUT_BF16)
                    ((__hip_bfloat16*)Cout)[(size_t)row * N + col] = __float2bfloat16(v);
                else
                    ((float*)Cout)[(size_t)row * N + col] = v;
            }
        }
    }
}

// ---------------- sliding-window flash attention ----------------
// block: 1 head x 64 queries (4 waves x 16 q rows). 5 key tiles of 64 cover
// [i0-256, i0+64). Online softmax in exp2 domain. QKV fused layout (ld=3072).
__global__ __launch_bounds__(256) void attn_k(const __hip_bfloat16* __restrict__ QKV,
                                              __hip_bfloat16* __restrict__ AO) {
    __shared__ __align__(16) __hip_bfloat16 Qs[64 * 72];
    __shared__ __align__(16) __hip_bfloat16 Ks[64 * 72];
    __shared__ __align__(16) __hip_bfloat16 Vt[64 * 72];  // transposed: [hd][key]
    __shared__ __align__(16) __hip_bfloat16 Ps[4 * 16 * 72];

    const int h = blockIdx.y;
    const int i0 = blockIdx.x * 64;
    const int t = threadIdx.x;
    const int wave = t >> 6, lane = t & 63;
    const int quad = lane >> 4, l16 = lane & 15;
    const float sc = 0.125f * 1.44269504088896f;  // 1/sqrt(64) * log2(e)

    const __hip_bfloat16* Q = QKV + h * HEAD_DIM;
    const __hip_bfloat16* K = QKV + D_MODEL + h * HEAD_DIM;
    const __hip_bfloat16* V = QKV + 2 * D_MODEL + h * HEAD_DIM;

    // stage Q tile [64 rows][64 hd]
    for (int c = t; c < 512; c += 256) {
        int row = c >> 3, c8 = (c & 7) * 8;
        *(uint4*)&Qs[row * 72 + c8] =
            *(const uint4*)(Q + (size_t)(i0 + row) * QKV_LD + c8);
    }
    __syncthreads();

    bf16x8 aq[2];
#pragma unroll
    for (int kk = 0; kk < 2; ++kk)
        aq[kk] = *(const bf16x8*)&Qs[(wave * 16 + l16) * 72 + kk * 32 + quad * 8];

    float mrow[4], lrow[4];
    f32x4 Ov[4];
#pragma unroll
    for (int r = 0; r < 4; ++r) { mrow[r] = -3.0e38f; lrow[r] = 0.f; }
#pragma unroll
    for (int no = 0; no < 4; ++no) Ov[no] = (f32x4){0.f, 0.f, 0.f, 0.f};

    // V-transpose coords: rowpair p = t>>3 (0..31), chunk c = t&7
    const int vp = t >> 3, vc = t & 7;

    for (int tt = 0; tt < 5; ++tt) {
        const int tb = i0 - WINDOW + tt * 64;
        if (tb < 0) continue;  // uniform across block

        // stage K tile (natural, uint4)
        for (int c = t; c < 512; c += 256) {
            int row = c >> 3, c8 = (c & 7) * 8;
            *(uint4*)&Ks[row * 72 + c8] =
                *(const uint4*)(K + (size_t)(tb + row) * QKV_LD + c8);
        }
        // stage V transposed: 2 rows packed per b32 write
        {
            uint4 v0 = *(const uint4*)(V + (size_t)(tb + 2 * vp) * QKV_LD + vc * 8);
            uint4 v1 = *(const uint4*)(V + (size_t)(tb + 2 * vp + 1) * QKV_LD + vc * 8);
            const unsigned short* a0 = (const unsigned short*)&v0;
            const unsigned short* a1 = (const unsigned short*)&v1;
#pragma unroll
            for (int j = 0; j < 8; ++j) {
                unsigned int pk = (unsigned int)a0[j] | ((unsigned int)a1[j] << 16);
                *(unsigned int*)&Vt[(vc * 8 + j) * 72 + 2 * vp] = pk;
            }
        }
        __syncthreads();

        // S = Q K^T  (M=16 q rows, N=64 keys, K=64 hd)
        f32x4 s[4];
#pragma unroll
        for (int ni = 0; ni < 4; ++ni) s[ni] = (f32x4){0.f, 0.f, 0.f, 0.f};
#pragma unroll
        for (int kk = 0; kk < 2; ++kk)
#pragma unroll
            for (int ni = 0; ni < 4; ++ni) {
                bf16x8 bk = *(const bf16x8*)&Ks[(ni * 16 + l16) * 72 + kk * 32 + quad * 8];
                s[ni] = __builtin_amdgcn_mfma_f32_16x16x32_bf16(aq[kk], bk, s[ni], 0, 0, 0);
            }

        // mask + online softmax (exp2 domain)
        const int irow0 = i0 + wave * 16 + quad * 4;
        float tv[4][4], rmax[4];
#pragma unroll
        for (int r = 0; r < 4; ++r) rmax[r] = -3.0e38f;
#pragma unroll
        for (int ni = 0; ni < 4; ++ni) {
            int j = tb + ni * 16 + l16;
#pragma unroll
            for (int r = 0; r < 4; ++r) {
                int i = irow0 + r;
                float v = s[ni][r] * sc;
                bool ok = (j <= i) && (i - j < WINDOW);
                v = ok ? v : -3.0e38f;
                tv[ni][r] = v;
                rmax[r] = fmaxf(rmax[r], v);
            }
        }
#pragma unroll
        for (int r = 0; r < 4; ++r) {
            rmax[r] = fmaxf(rmax[r], __shfl_xor(rmax[r], 1));
            rmax[r] = fmaxf(rmax[r], __shfl_xor(rmax[r], 2));
            rmax[r] = fmaxf(rmax[r], __shfl_xor(rmax[r], 4));
            rmax[r] = fmaxf(rmax[r], __shfl_xor(rmax[r], 8));
        }
        float alpha[4], rsum[4];
#pragma unroll
        for (int r = 0; r < 4; ++r) {
            float mn = fmaxf(mrow[r], rmax[r]);
            alpha[r] = exp2f(mrow[r] - mn);
            mrow[r] = mn;
            rsum[r] = 0.f;
        }
        float p[4][4];
#pragma unroll
        for (int ni = 0; ni < 4; ++ni)
#pragma unroll
            for (int r = 0; r < 4; ++r) {
                p[ni][r] = exp2f(tv[ni][r] - mrow[r]);
                rsum[r] += p[ni][r];
            }
#pragma unroll
        for (int r = 0; r < 4; ++r) {
            rsum[r] += __shfl_xor(rsum[r], 1);
            rsum[r] += __shfl_xor(rsum[r], 2);
            rsum[r] += __shfl_xor(rsum[r], 4);
            rsum[r] += __shfl_xor(rsum[r], 8);
            lrow[r] = lrow[r] * alpha[r] + rsum[r];
        }
#pragma unroll
        for (int no = 0; no < 4; ++no)
#pragma unroll
            for (int r = 0; r < 4; ++r) Ov[no][r] *= alpha[r];

        // P: C-layout -> LDS -> A-layout (per-wave region)
#pragma unroll
        for (int ni = 0; ni < 4; ++ni)
#pragma unroll
            for (int r = 0; r < 4; ++r)
                Ps[(wave * 16 + quad * 4 + r) * 72 + ni * 16 + l16] =
                    __float2bfloat16(p[ni][r]);

        // O += P V  (M=16, N=64 hd, K=64 keys)
#pragma unroll
        for (int kk = 0; kk < 2; ++kk) {
            bf16x8 ap = *(const bf16x8*)&Ps[(wave * 16 + l16) * 72 + kk * 32 + quad * 8];
#pragma unroll
            for (int no = 0; no < 4; ++no) {
                bf16x8 bv = *(const bf16x8*)&Vt[(no * 16 + l16) * 72 + kk * 32 + quad * 8];
                Ov[no] = __builtin_amdgcn_mfma_f32_16x16x32_bf16(ap, bv, Ov[no], 0, 0, 0);
            }
        }
        __syncthreads();  // protect Ks/Vt before next tile's staging
    }

    // normalize + store
    float inv[4];
#pragma unroll
    for (int r = 0; r < 4; ++r) inv[r] = 1.0f / lrow[r];
#pragma unroll
    for (int no = 0; no < 4; ++no)
#pragma unroll
        for (int r = 0; r < 4; ++r) {
            int i = i0 + wave * 16 + quad * 4 + r;
            AO[(size_t)i * D_MODEL + h * HEAD_DIM + no * 16 + l16] =
                __float2bfloat16(Ov[no][r] * inv[r]);
        }
}

// ---------------------------------------------------------------------------
extern "C" void kernel_launch(void* const* d_in, const int* in_sizes, int n_in,
                              void* d_out, int out_size, void* d_ws, size_t ws_size,
                              hipStream_t stream) {
    const float* x  = (const float*)d_in[0];
    const float* Wq = (const float*)d_in[1];
    const float* Wk = (const float*)d_in[2];
    const float* Wv = (const float*)d_in[3];
    const float* Wo = (const float*)d_in[4];
    const float* bq = (const float*)d_in[5];
    const float* bk = (const float*)d_in[6];
    const float* bv = (const float*)d_in[7];
    const float* bo = (const float*)d_in[8];
    float* out = (float*)d_out;

    char* w = (char*)d_ws;
    const size_t MB = 1u << 20;
    __hip_bfloat16* xb    = (__hip_bfloat16*)(w + 0 * MB);   // 8 MB
    __hip_bfloat16* Wqkvt = (__hip_bfloat16*)(w + 8 * MB);   // 6 MB [3072][1024]
    __hip_bfloat16* Wot   = (__hip_bfloat16*)(w + 14 * MB);  // 2 MB
    float*          bcat  = (float*)(w + 16 * MB);           // 12 KB
    __hip_bfloat16* QKV   = (__hip_bfloat16*)(w + 17 * MB);  // 24 MB [4096][3072]
    __hip_bfloat16* AO    = (__hip_bfloat16*)(w + 41 * MB);  // 8 MB, end 49 MB

    // prep: x cast + 4 transposes + bias concat (1 launch)
    prep_k<<<3073, 256, 0, stream>>>(x, Wq, Wk, Wv, Wo, bq, bk, bv,
                                     (unsigned short*)xb, Wqkvt, Wot, bcat);

    // fused QKV projection: [4096][1024] x [3072][1024]^T -> [4096][3072]
    dim3 gqkv(QKV_LD / 128, S_LEN / 128);
    gemm_bias_k<true><<<gqkv, 256, 0, stream>>>(xb, Wqkvt, bcat, QKV,
                                                S_LEN, QKV_LD, D_MODEL);

    // attention
    dim3 ag(S_LEN / 64, N_HEADS);
    attn_k<<<ag, 256, 0, stream>>>(QKV, AO);

    // output projection -> f32
    dim3 go(D_MODEL / 128, S_LEN / 128);
    gemm_bias_k<false><<<go, 256, 0, stream>>>(AO, Wot, bo, out,
                                               S_LEN, D_MODEL, D_MODEL);
}